// Round 1
// baseline (1356.328 us; speedup 1.0000x reference)
//
#include <hip/hip_runtime.h>

#define WAVES_PER_BLOCK 4

// Wave = one sample, lane = one hidden unit (W=64 == wavefront size).
// Per Euler step:
//   layer0 (per lane): z0 = W0.[y1,y2,t]+b0; silu value + s1,s2 derivatives
//   4 channels packed in float4: {u0, s1*W0[:,0], s1*W0[:,1], s2*(W0[:,0]^2+W0[:,1]^2)}
//   layer1 (per lane j): 4-channel matvec against register-resident W1 row j,
//   u0 channels broadcast from wave-private LDS (uniform-address b128 reads)
//   layer2: f1,f2,tr partials reduced across 64 lanes via shfl_xor butterfly
__global__ __launch_bounds__(WAVES_PER_BLOCK * 64)
void cnf_kernel(const float* __restrict__ yin,
                const float* __restrict__ eW0, const float* __restrict__ eb0,
                const float* __restrict__ eW1, const float* __restrict__ eb1,
                const float* __restrict__ eW2,
                const float* __restrict__ dW0, const float* __restrict__ db0,
                const float* __restrict__ dW1, const float* __restrict__ db1,
                const float* __restrict__ dW2,
                const int* __restrict__ t1p,
                float* __restrict__ out, int nsamp)
{
    __shared__ float4 ubuf[WAVES_PER_BLOCK][64];
    const int lane = threadIdx.x & 63;
    const int wid  = threadIdx.x >> 6;
    const int s    = blockIdx.x * WAVES_PER_BLOCK + wid;

    float y1 = yin[2 * s];
    float y2 = yin[2 * s + 1];
    float lp = 0.0f;
    const int t1 = *t1p;

    for (int ph = 0; ph < 2; ++ph) {
        const float* W0 = ph ? dW0 : eW0;
        const float* B0 = ph ? db0 : eb0;
        const float* W1 = ph ? dW1 : eW1;
        const float* B1 = ph ? db1 : eb1;
        const float* W2 = ph ? dW2 : eW2;
        const int nsteps = ph ? t1 : 10;

        // per-lane (per-hidden-unit) weights
        const float w00 = W0[3 * lane + 0];
        const float w01 = W0[3 * lane + 1];
        const float w02 = W0[3 * lane + 2];
        const float b0r = B0[lane];
        const float b1r = B1[lane];
        const float w2r = W2[lane];
        const float qsum = w00 * w00 + w01 * w01;

        // W1 row `lane` resident in 64 VGPRs
        float4 w1r[16];
        {
            const float4* g = (const float4*)(W1 + 64 * lane);
            #pragma unroll
            for (int m = 0; m < 16; ++m) w1r[m] = g[m];
        }

        float t = 0.0f;
        for (int n = 0; n < nsteps; ++n) {
            // ---- layer 0 ----
            float z  = fmaf(w00, y1, fmaf(w01, y2, fmaf(w02, t, b0r)));
            float e  = __expf(-z);
            float sg = __builtin_amdgcn_rcpf(1.0f + e);       // sigmoid(z)
            float sp = sg * (1.0f - sg);
            float s1 = fmaf(z, sp, sg);                       // silu'(z)
            float s2 = sp * fmaf(z, fmaf(-2.0f, sg, 1.0f), 2.0f); // silu''(z)
            float4 uw;
            uw.x = z * sg;        // u0 value
            uw.y = s1 * w00;      // du0/dy1
            uw.z = s1 * w01;      // du0/dy2
            uw.w = s2 * qsum;     // summed Hessian-diagonal channel
            __builtin_amdgcn_wave_barrier();
            ubuf[wid][lane] = uw;
            __builtin_amdgcn_wave_barrier();

            // ---- layer 1: 4-channel matvec, row `lane` ----
            float zv = b1r, zg1 = 0.0f, zg2 = 0.0f, zh = 0.0f;
            #pragma unroll
            for (int kk = 0; kk < 16; ++kk) {
                float4 w  = w1r[kk];
                float4 u0 = ubuf[wid][4 * kk + 0];
                float4 u1 = ubuf[wid][4 * kk + 1];
                float4 u2 = ubuf[wid][4 * kk + 2];
                float4 u3 = ubuf[wid][4 * kk + 3];
                zv  = fmaf(w.x, u0.x, zv);  zg1 = fmaf(w.x, u0.y, zg1);
                zg2 = fmaf(w.x, u0.z, zg2); zh  = fmaf(w.x, u0.w, zh);
                zv  = fmaf(w.y, u1.x, zv);  zg1 = fmaf(w.y, u1.y, zg1);
                zg2 = fmaf(w.y, u1.z, zg2); zh  = fmaf(w.y, u1.w, zh);
                zv  = fmaf(w.z, u2.x, zv);  zg1 = fmaf(w.z, u2.y, zg1);
                zg2 = fmaf(w.z, u2.z, zg2); zh  = fmaf(w.z, u2.w, zh);
                zv  = fmaf(w.w, u3.x, zv);  zg1 = fmaf(w.w, u3.y, zg1);
                zg2 = fmaf(w.w, u3.z, zg2); zh  = fmaf(w.w, u3.w, zh);
            }

            // ---- layer 1 nonlinearity + layer 2 partial products ----
            float e1  = __expf(-zv);
            float sg1 = __builtin_amdgcn_rcpf(1.0f + e1);
            float spp = sg1 * (1.0f - sg1);
            float s1b = fmaf(zv, spp, sg1);
            float s2b = spp * fmaf(zv, fmaf(-2.0f, sg1, 1.0f), 2.0f);
            float a   = w2r * s1b;
            float f1p = a * zg1;
            float f2p = a * zg2;
            float trp = fmaf(w2r * s2b, fmaf(zg1, zg1, zg2 * zg2), a * zh);

            // ---- 64-lane butterfly reduction (all lanes get the sums) ----
            #pragma unroll
            for (int off = 32; off > 0; off >>= 1) {
                f1p += __shfl_xor(f1p, off);
                f2p += __shfl_xor(f2p, off);
                trp += __shfl_xor(trp, off);
            }

            y1 += f1p;   // dt = 1.0
            y2 += f2p;
            lp += trp;
            t  += 1.0f;
        }
    }

    if (lane == 0) {
        out[2 * s]         = y1;
        out[2 * s + 1]     = y2;
        out[2 * nsamp + s] = lp;
    }
}

extern "C" void kernel_launch(void* const* d_in, const int* in_sizes, int n_in,
                              void* d_out, int out_size, void* d_ws, size_t ws_size,
                              hipStream_t stream)
{
    const float* y   = (const float*)d_in[0];
    const float* eW0 = (const float*)d_in[1];
    const float* eb0 = (const float*)d_in[2];
    const float* eW1 = (const float*)d_in[3];
    const float* eb1 = (const float*)d_in[4];
    const float* eW2 = (const float*)d_in[5];
    // d_in[6] = eb2 (no effect on drift/trace)
    const float* dW0 = (const float*)d_in[7];
    const float* db0 = (const float*)d_in[8];
    const float* dW1 = (const float*)d_in[9];
    const float* db1 = (const float*)d_in[10];
    const float* dW2 = (const float*)d_in[11];
    // d_in[12] = db2 (no effect)
    const int* t1 = (const int*)d_in[13];

    float* out = (float*)d_out;
    const int nsamp = in_sizes[0] / 2;   // 32768
    const int blocks = nsamp / WAVES_PER_BLOCK;

    cnf_kernel<<<blocks, WAVES_PER_BLOCK * 64, 0, stream>>>(
        y, eW0, eb0, eW1, eb1, eW2, dW0, db0, dW1, db1, dW2, t1, out, nsamp);
}

// Round 2
// 74.920 us; speedup vs baseline: 18.1036x; 18.1036x over previous
//
#include <hip/hip_runtime.h>

typedef __attribute__((ext_vector_type(4))) float f32x4;
typedef __attribute__((ext_vector_type(8))) short bf16x8;

// round-to-nearest-even fp32 -> bf16 (finite inputs only)
static __device__ __forceinline__ short f2bf(float f) {
    unsigned u = __builtin_bit_cast(unsigned, f);
    u = u + 0x7FFFu + ((u >> 16) & 1u);
    return (short)(u >> 16);
}

// Wave = 16 samples. Lane l: sample sl = l&15, group g = l>>4.
// GEMM per step: Z1[j,s] = sum_k W1[j,k] * U[k,s]  (4 channels, K=64)
//   A = W1: lane holds A[j = sl + 16*tp][k = g*8 + e + 32*c]  (bf16x8 frags, static)
//   B = U : lane holds U[k = g*8 + e + 32*c][sample sl]  -> lane computes layer0
//           for exactly its own B elements. No LDS anywhere.
//   C/D  : col = lane&15 (sample), row j = 16*tp + 4*g + r   [m89-verified]
// Epilogue: per-lane partial sums over its 16 j's, then shfl_xor(16,32).
__global__ __launch_bounds__(256, 2)
void cnf_kernel(const float* __restrict__ yin,
                const float* __restrict__ eW0, const float* __restrict__ eb0,
                const float* __restrict__ eW1, const float* __restrict__ eb1,
                const float* __restrict__ eW2,
                const float* __restrict__ dW0, const float* __restrict__ db0,
                const float* __restrict__ dW1, const float* __restrict__ db1,
                const float* __restrict__ dW2,
                const int* __restrict__ t1p,
                float* __restrict__ out, int nsamp)
{
    const int lane  = threadIdx.x & 63;
    const int wid   = threadIdx.x >> 6;
    const int wavei = blockIdx.x * 4 + wid;
    const int sl    = lane & 15;   // sample within wave; also A-row base
    const int g     = lane >> 4;   // lane group
    const int s     = wavei * 16 + sl;

    float y1 = yin[2 * s];
    float y2 = yin[2 * s + 1];
    float lp = 0.0f;
    const int t1 = *t1p;

    for (int ph = 0; ph < 2; ++ph) {
        const float* W0 = ph ? dW0 : eW0;
        const float* B0 = ph ? db0 : eb0;
        const float* W1 = ph ? dW1 : eW1;
        const float* B1 = ph ? db1 : eb1;
        const float* W2 = ph ? dW2 : eW2;
        const int nsteps = ph ? t1 : 10;

        // ---- static A fragments: W1 tiles in bf16 ----
        bf16x8 afrag[4][2];
        #pragma unroll
        for (int tp = 0; tp < 4; ++tp) {
            #pragma unroll
            for (int c = 0; c < 2; ++c) {
                const float* p = W1 + (sl + 16 * tp) * 64 + g * 8 + 32 * c;
                f32x4 lo = *(const f32x4*)p;
                f32x4 hi = *(const f32x4*)(p + 4);
                bf16x8 a;
                a[0] = f2bf(lo[0]); a[1] = f2bf(lo[1]);
                a[2] = f2bf(lo[2]); a[3] = f2bf(lo[3]);
                a[4] = f2bf(hi[0]); a[5] = f2bf(hi[1]);
                a[6] = f2bf(hi[2]); a[7] = f2bf(hi[3]);
                afrag[tp][c] = a;
            }
        }

        // ---- per-lane W0 params for its 16 k's (k = g*8 + e + 32*c) ----
        float p00[16], p01[16], p02[16], pb0[16];
        #pragma unroll
        for (int c = 0; c < 2; ++c) {
            const int kb = g * 8 + 32 * c;
            const float* p = W0 + 3 * kb;          // 24 contiguous floats
            float buf[24];
            #pragma unroll
            for (int q = 0; q < 6; ++q) {
                f32x4 v = ((const f32x4*)p)[q];
                buf[4*q+0] = v[0]; buf[4*q+1] = v[1];
                buf[4*q+2] = v[2]; buf[4*q+3] = v[3];
            }
            #pragma unroll
            for (int e = 0; e < 8; ++e) {
                p00[c*8+e] = buf[3*e+0];
                p01[c*8+e] = buf[3*e+1];
                p02[c*8+e] = buf[3*e+2];
            }
            f32x4 ba = *(const f32x4*)(B0 + kb);
            f32x4 bb = *(const f32x4*)(B0 + kb + 4);
            #pragma unroll
            for (int e = 0; e < 4; ++e) {
                pb0[c*8+e]   = ba[e];
                pb0[c*8+4+e] = bb[e];
            }
        }

        // ---- layer-2 params for this lane's 16 j's (j = 16*tp + 4*g + r) ----
        f32x4 b1v[4], w2v[4];
        #pragma unroll
        for (int tp = 0; tp < 4; ++tp) {
            b1v[tp] = *(const f32x4*)(B1 + 16 * tp + 4 * g);
            w2v[tp] = *(const f32x4*)(W2 + 16 * tp + 4 * g);
        }

        float tt = 0.0f;
        for (int n = 0; n < nsteps; ++n) {
            // ---- layer 0: build all B fragments (both k-chunks, 4 channels) ----
            bf16x8 Bv[2], Bg1[2], Bg2[2], Bh[2];
            #pragma unroll
            for (int c = 0; c < 2; ++c) {
                #pragma unroll
                for (int e = 0; e < 8; ++e) {
                    const int i = c * 8 + e;
                    float z  = fmaf(p00[i], y1, fmaf(p01[i], y2, fmaf(p02[i], tt, pb0[i])));
                    float ex = __expf(-z);
                    float sg = __builtin_amdgcn_rcpf(1.0f + ex);
                    float sp = sg * (1.0f - sg);
                    float s1 = fmaf(z, sp, sg);                            // silu'
                    float s2 = sp * fmaf(z, fmaf(-2.0f, sg, 1.0f), 2.0f);  // silu''
                    Bv[c][e]  = f2bf(z * sg);
                    Bg1[c][e] = f2bf(s1 * p00[i]);
                    Bg2[c][e] = f2bf(s1 * p01[i]);
                    Bh[c][e]  = f2bf(s2 * fmaf(p00[i], p00[i], p01[i] * p01[i]));
                }
            }

            // ---- MFMA + epilogue, two j-tile pairs (halves acc register life) ----
            float f1 = 0.0f, f2 = 0.0f, trp = 0.0f;
            #pragma unroll
            for (int hp = 0; hp < 2; ++hp) {
                f32x4 av[2], ag1[2], ag2[2], ah[2];
                #pragma unroll
                for (int u = 0; u < 2; ++u) {
                    const int tp = hp * 2 + u;
                    av[u]  = b1v[tp];
                    ag1[u] = f32x4{0.f, 0.f, 0.f, 0.f};
                    ag2[u] = f32x4{0.f, 0.f, 0.f, 0.f};
                    ah[u]  = f32x4{0.f, 0.f, 0.f, 0.f};
                    #pragma unroll
                    for (int c = 0; c < 2; ++c) {
                        av[u]  = __builtin_amdgcn_mfma_f32_16x16x32_bf16(afrag[tp][c], Bv[c],  av[u],  0, 0, 0);
                        ag1[u] = __builtin_amdgcn_mfma_f32_16x16x32_bf16(afrag[tp][c], Bg1[c], ag1[u], 0, 0, 0);
                        ag2[u] = __builtin_amdgcn_mfma_f32_16x16x32_bf16(afrag[tp][c], Bg2[c], ag2[u], 0, 0, 0);
                        ah[u]  = __builtin_amdgcn_mfma_f32_16x16x32_bf16(afrag[tp][c], Bh[c],  ah[u],  0, 0, 0);
                    }
                }
                #pragma unroll
                for (int u = 0; u < 2; ++u) {
                    const int tp = hp * 2 + u;
                    #pragma unroll
                    for (int r = 0; r < 4; ++r) {
                        float zv  = av[u][r];
                        float ex  = __expf(-zv);
                        float sg  = __builtin_amdgcn_rcpf(1.0f + ex);
                        float sp  = sg * (1.0f - sg);
                        float s1b = fmaf(zv, sp, sg);
                        float s2b = sp * fmaf(zv, fmaf(-2.0f, sg, 1.0f), 2.0f);
                        float w2  = w2v[tp][r];
                        float a   = w2 * s1b;
                        float zg1 = ag1[u][r], zg2 = ag2[u][r];
                        f1  = fmaf(a, zg1, f1);
                        f2  = fmaf(a, zg2, f2);
                        trp = fmaf(w2 * s2b, fmaf(zg1, zg1, zg2 * zg2),
                                   fmaf(a, ah[u][r], trp));
                    }
                }
            }

            // ---- reduce over the 4 lane groups (j covered disjointly) ----
            f1  += __shfl_xor(f1, 16);  f1  += __shfl_xor(f1, 32);
            f2  += __shfl_xor(f2, 16);  f2  += __shfl_xor(f2, 32);
            trp += __shfl_xor(trp, 16); trp += __shfl_xor(trp, 32);

            y1 += f1;    // dt = 1.0
            y2 += f2;
            lp += trp;
            tt += 1.0f;
        }
    }

    if (lane < 16) {
        out[2 * s]         = y1;
        out[2 * s + 1]     = y2;
        out[2 * nsamp + s] = lp;
    }
}

extern "C" void kernel_launch(void* const* d_in, const int* in_sizes, int n_in,
                              void* d_out, int out_size, void* d_ws, size_t ws_size,
                              hipStream_t stream)
{
    const float* y   = (const float*)d_in[0];
    const float* eW0 = (const float*)d_in[1];
    const float* eb0 = (const float*)d_in[2];
    const float* eW1 = (const float*)d_in[3];
    const float* eb1 = (const float*)d_in[4];
    const float* eW2 = (const float*)d_in[5];
    // d_in[6] = eb2 (no effect on drift/trace)
    const float* dW0 = (const float*)d_in[7];
    const float* db0 = (const float*)d_in[8];
    const float* dW1 = (const float*)d_in[9];
    const float* db1 = (const float*)d_in[10];
    const float* dW2 = (const float*)d_in[11];
    // d_in[12] = db2 (no effect)
    const int* t1 = (const int*)d_in[13];

    float* out = (float*)d_out;
    const int nsamp = in_sizes[0] / 2;         // 32768
    const int blocks = nsamp / 64;             // 4 waves/block, 16 samples/wave

    cnf_kernel<<<blocks, 256, 0, stream>>>(
        y, eW0, eb0, eW1, eb1, eW2, dW0, db0, dW1, db1, dW2, t1, out, nsamp);
}

// Round 3
// 73.247 us; speedup vs baseline: 18.5171x; 1.0228x over previous
//
#include <hip/hip_runtime.h>

typedef __attribute__((ext_vector_type(4))) float f32x4;
typedef __attribute__((ext_vector_type(8))) short bf16x8;
typedef __attribute__((ext_vector_type(4))) unsigned u32x4;

// pack two fp32 -> two bf16 (round-half-up; <=0.5ulp vs RTNE, plenty for our threshold)
static __device__ __forceinline__ unsigned bfpack(float a, float b) {
    unsigned ua = __builtin_bit_cast(unsigned, a) + 0x8000u;
    unsigned ub = __builtin_bit_cast(unsigned, b) + 0x8000u;
    return (ua >> 16) | (ub & 0xFFFF0000u);
}

// Wave = 16 samples. Lane l: sample sl = l&15, group g = l>>4.
// GEMM per step: Z1[j,s] = sum_k W1[j,k] * U[k,s]  (4 channels, K=64)
//   A = W1: lane holds A[j = sl + 16*tp][k = g*8 + e + 32*c]  (bf16x8 frags, static)
//   B = U : lane holds U[k = g*8 + e + 32*c][sample sl]  -> layer0 computed
//           exactly for the lane's own B elements. No LDS anywhere.
//   C/D  : col = lane&15 (sample), row j = 16*tp + 4*g + r   [m89-verified]
// Epilogue: per-lane partial sums over its 16 j's, then shfl_xor(16,32).
__global__ __launch_bounds__(256, 2)
void cnf_kernel(const float* __restrict__ yin,
                const float* __restrict__ eW0, const float* __restrict__ eb0,
                const float* __restrict__ eW1, const float* __restrict__ eb1,
                const float* __restrict__ eW2,
                const float* __restrict__ dW0, const float* __restrict__ db0,
                const float* __restrict__ dW1, const float* __restrict__ db1,
                const float* __restrict__ dW2,
                const int* __restrict__ t1p,
                float* __restrict__ out, int nsamp)
{
    const int lane  = threadIdx.x & 63;
    const int wid   = threadIdx.x >> 6;
    const int wavei = blockIdx.x * 4 + wid;
    const int sl    = lane & 15;   // sample within wave; also A-row base
    const int g     = lane >> 4;   // lane group
    const int s     = wavei * 16 + sl;

    float y1 = yin[2 * s];
    float y2 = yin[2 * s + 1];
    float lp = 0.0f;
    const int t1 = *t1p;

    for (int ph = 0; ph < 2; ++ph) {
        const float* W0 = ph ? dW0 : eW0;
        const float* B0 = ph ? db0 : eb0;
        const float* W1 = ph ? dW1 : eW1;
        const float* B1 = ph ? db1 : eb1;
        const float* W2 = ph ? dW2 : eW2;
        const int nsteps = ph ? t1 : 10;

        // ---- static A fragments: W1 tiles in bf16 ----
        bf16x8 afrag[4][2];
        #pragma unroll
        for (int tp = 0; tp < 4; ++tp) {
            #pragma unroll
            for (int c = 0; c < 2; ++c) {
                const float* p = W1 + (sl + 16 * tp) * 64 + g * 8 + 32 * c;
                f32x4 lo = *(const f32x4*)p;
                f32x4 hi = *(const f32x4*)(p + 4);
                u32x4 a;
                a[0] = bfpack(lo[0], lo[1]);
                a[1] = bfpack(lo[2], lo[3]);
                a[2] = bfpack(hi[0], hi[1]);
                a[3] = bfpack(hi[2], hi[3]);
                afrag[tp][c] = __builtin_bit_cast(bf16x8, a);
            }
        }

        // ---- per-lane W0 params for its 16 k's (k = g*8 + e + 32*c) ----
        // tb[i] = w02*t + b0 maintained incrementally (t starts at 0)
        float p00[16], p01[16], p02[16], tb[16], pq[16];
        #pragma unroll
        for (int c = 0; c < 2; ++c) {
            const int kb = g * 8 + 32 * c;
            const float* p = W0 + 3 * kb;          // 24 contiguous floats
            float buf[24];
            #pragma unroll
            for (int q = 0; q < 6; ++q) {
                f32x4 v = ((const f32x4*)p)[q];
                buf[4*q+0] = v[0]; buf[4*q+1] = v[1];
                buf[4*q+2] = v[2]; buf[4*q+3] = v[3];
            }
            #pragma unroll
            for (int e = 0; e < 8; ++e) {
                p00[c*8+e] = buf[3*e+0];
                p01[c*8+e] = buf[3*e+1];
                p02[c*8+e] = buf[3*e+2];
                pq[c*8+e]  = fmaf(buf[3*e+0], buf[3*e+0], buf[3*e+1] * buf[3*e+1]);
            }
            f32x4 ba = *(const f32x4*)(B0 + kb);
            f32x4 bb = *(const f32x4*)(B0 + kb + 4);
            #pragma unroll
            for (int e = 0; e < 4; ++e) {
                tb[c*8+e]   = ba[e];
                tb[c*8+4+e] = bb[e];
            }
        }

        // ---- layer-2 params for this lane's 16 j's (j = 16*tp + 4*g + r) ----
        f32x4 b1v[4], w2v[4];
        #pragma unroll
        for (int tp = 0; tp < 4; ++tp) {
            b1v[tp] = *(const f32x4*)(B1 + 16 * tp + 4 * g);
            w2v[tp] = *(const f32x4*)(W2 + 16 * tp + 4 * g);
        }

        for (int n = 0; n < nsteps; ++n) {
            // ---- layer 0: build all B fragments (both k-chunks, 4 channels) ----
            bf16x8 Bv[2], Bg1[2], Bg2[2], Bh[2];
            #pragma unroll
            for (int c = 0; c < 2; ++c) {
                u32x4 qv, qg1, qg2, qh;
                #pragma unroll
                for (int e = 0; e < 8; e += 2) {
                    const int i0 = c * 8 + e, i1 = i0 + 1;
                    float z0  = fmaf(p00[i0], y1, fmaf(p01[i0], y2, tb[i0]));
                    float ex0 = __expf(-z0);
                    float sA  = __builtin_amdgcn_rcpf(1.0f + ex0);
                    float spA = fmaf(-sA, sA, sA);
                    float s1A = fmaf(z0, spA, sA);
                    float s2A = spA * fmaf(z0, fmaf(-2.0f, sA, 1.0f), 2.0f);

                    float z1  = fmaf(p00[i1], y1, fmaf(p01[i1], y2, tb[i1]));
                    float ex1 = __expf(-z1);
                    float sB  = __builtin_amdgcn_rcpf(1.0f + ex1);
                    float spB = fmaf(-sB, sB, sB);
                    float s1B = fmaf(z1, spB, sB);
                    float s2B = spB * fmaf(z1, fmaf(-2.0f, sB, 1.0f), 2.0f);

                    qv[e >> 1]  = bfpack(z0 * sA,       z1 * sB);
                    qg1[e >> 1] = bfpack(s1A * p00[i0], s1B * p00[i1]);
                    qg2[e >> 1] = bfpack(s1A * p01[i0], s1B * p01[i1]);
                    qh[e >> 1]  = bfpack(s2A * pq[i0],  s2B * pq[i1]);
                }
                Bv[c]  = __builtin_bit_cast(bf16x8, qv);
                Bg1[c] = __builtin_bit_cast(bf16x8, qg1);
                Bg2[c] = __builtin_bit_cast(bf16x8, qg2);
                Bh[c]  = __builtin_bit_cast(bf16x8, qh);
            }

            // ---- MFMA + epilogue, two j-tile pairs (halves acc register life) ----
            float f1 = 0.0f, f2 = 0.0f, trp = 0.0f;
            #pragma unroll
            for (int hp = 0; hp < 2; ++hp) {
                f32x4 av[2], ag1[2], ag2[2], ah[2];
                #pragma unroll
                for (int u = 0; u < 2; ++u) {
                    const int tp = hp * 2 + u;
                    av[u]  = b1v[tp];
                    ag1[u] = f32x4{0.f, 0.f, 0.f, 0.f};
                    ag2[u] = f32x4{0.f, 0.f, 0.f, 0.f};
                    ah[u]  = f32x4{0.f, 0.f, 0.f, 0.f};
                    #pragma unroll
                    for (int c = 0; c < 2; ++c) {
                        av[u]  = __builtin_amdgcn_mfma_f32_16x16x32_bf16(afrag[tp][c], Bv[c],  av[u],  0, 0, 0);
                        ag1[u] = __builtin_amdgcn_mfma_f32_16x16x32_bf16(afrag[tp][c], Bg1[c], ag1[u], 0, 0, 0);
                        ag2[u] = __builtin_amdgcn_mfma_f32_16x16x32_bf16(afrag[tp][c], Bg2[c], ag2[u], 0, 0, 0);
                        ah[u]  = __builtin_amdgcn_mfma_f32_16x16x32_bf16(afrag[tp][c], Bh[c],  ah[u],  0, 0, 0);
                    }
                }
                #pragma unroll
                for (int u = 0; u < 2; ++u) {
                    const int tp = hp * 2 + u;
                    #pragma unroll
                    for (int r = 0; r < 4; ++r) {
                        float zv  = av[u][r];
                        float exv = __expf(-zv);
                        float sgv = __builtin_amdgcn_rcpf(1.0f + exv);
                        float spv = fmaf(-sgv, sgv, sgv);
                        float s1b = fmaf(zv, spv, sgv);
                        float s2b = spv * fmaf(zv, fmaf(-2.0f, sgv, 1.0f), 2.0f);
                        float w2  = w2v[tp][r];
                        float c1  = w2 * s1b;
                        float c2  = w2 * s2b;
                        float zg1 = ag1[u][r], zg2 = ag2[u][r];
                        f1  = fmaf(c1, zg1, f1);
                        f2  = fmaf(c1, zg2, f2);
                        trp = fmaf(c2, fmaf(zg1, zg1, zg2 * zg2),
                                   fmaf(c1, ah[u][r], trp));
                    }
                }
            }

            // ---- reduce over the 4 lane groups (j covered disjointly) ----
            f1  += __shfl_xor(f1, 16);  f1  += __shfl_xor(f1, 32);
            f2  += __shfl_xor(f2, 16);  f2  += __shfl_xor(f2, 32);
            trp += __shfl_xor(trp, 16); trp += __shfl_xor(trp, 32);

            y1 += f1;    // dt = 1.0
            y2 += f2;
            lp += trp;
            #pragma unroll
            for (int i = 0; i < 16; ++i) tb[i] += p02[i];   // t advances by dt=1
        }
    }

    if (lane < 16) {
        out[2 * s]         = y1;
        out[2 * s + 1]     = y2;
        out[2 * nsamp + s] = lp;
    }
}

extern "C" void kernel_launch(void* const* d_in, const int* in_sizes, int n_in,
                              void* d_out, int out_size, void* d_ws, size_t ws_size,
                              hipStream_t stream)
{
    const float* y   = (const float*)d_in[0];
    const float* eW0 = (const float*)d_in[1];
    const float* eb0 = (const float*)d_in[2];
    const float* eW1 = (const float*)d_in[3];
    const float* eb1 = (const float*)d_in[4];
    const float* eW2 = (const float*)d_in[5];
    // d_in[6] = eb2 (no effect on drift/trace)
    const float* dW0 = (const float*)d_in[7];
    const float* db0 = (const float*)d_in[8];
    const float* dW1 = (const float*)d_in[9];
    const float* db1 = (const float*)d_in[10];
    const float* dW2 = (const float*)d_in[11];
    // d_in[12] = db2 (no effect)
    const int* t1 = (const int*)d_in[13];

    float* out = (float*)d_out;
    const int nsamp = in_sizes[0] / 2;         // 32768
    const int blocks = nsamp / 64;             // 4 waves/block, 16 samples/wave

    cnf_kernel<<<blocks, 256, 0, stream>>>(
        y, eW0, eb0, eW1, eb1, eW2, dW0, db0, dW1, db1, dW2, t1, out, nsamp);
}